// Round 2
// baseline (307.485 us; speedup 1.0000x reference)
//
#include <hip/hip_runtime.h>
#include <cstdint>
#include <cstddef>

#define NB   4
#define NP   4096
#define OD   128

typedef _Float16 h16;
typedef _Float16 h16x8 __attribute__((ext_vector_type(8)));
typedef _Float16 h16x4 __attribute__((ext_vector_type(4)));
typedef float    f32x4 __attribute__((ext_vector_type(4)));

__device__ __forceinline__ void async16(const void* g, void* l) {
    __builtin_amdgcn_global_load_lds(
        (const __attribute__((address_space(1))) void*)g,
        (__attribute__((address_space(3))) void*)l, 16, 0, 0);
}

#define DPP_ROR(x, amt) __builtin_amdgcn_mov_dpp((x), 0x120 + (amt), 0xF, 0xF, false)

__device__ __forceinline__ float rmax16(float v) {
    v = fmaxf(v, __int_as_float(DPP_ROR(__float_as_int(v), 1)));
    v = fmaxf(v, __int_as_float(DPP_ROR(__float_as_int(v), 2)));
    v = fmaxf(v, __int_as_float(DPP_ROR(__float_as_int(v), 4)));
    v = fmaxf(v, __int_as_float(DPP_ROR(__float_as_int(v), 8)));
    return v;
}
__device__ __forceinline__ float rsum16(float v) {
    v += __int_as_float(DPP_ROR(__float_as_int(v), 1));
    v += __int_as_float(DPP_ROR(__float_as_int(v), 2));
    v += __int_as_float(DPP_ROR(__float_as_int(v), 4));
    v += __int_as_float(DPP_ROR(__float_as_int(v), 8));
    return v;
}

// ---------------------------------------------------------------------------
// W fp32 -> fp16, laid out as the exact LDS image conv wants (swizzled chunks):
// per (mat, kc): 512 slots of 16B; slot = o*4 + (c ^ ((o>>1)&3)), c = 8-half chunk.
// ---------------------------------------------------------------------------
__global__ __launch_bounds__(256) void wcvt(
    const float* __restrict__ Wq, const float* __restrict__ Wk,
    const float* __restrict__ Wv, h16* __restrict__ W16s)
{
    int g = blockIdx.x * 256 + threadIdx.x;        // 49152 slots total
    int mat = g >> 14, r = g & 16383;
    int kc = r >> 9, q = r & 511, o = q >> 2, csw = q & 3;
    int c = csw ^ ((o >> 1) & 3);
    const float* W = (mat == 0) ? Wq : (mat == 1) ? Wk : Wv;
    const float* src = W + (size_t)o * 1024 + kc * 32 + 8 * c;
    f32x4 a = *(const f32x4*)src;
    f32x4 b = *(const f32x4*)(src + 4);
    h16x8 h = {(h16)a.x, (h16)a.y, (h16)a.z, (h16)a.w,
               (h16)b.x, (h16)b.y, (h16)b.z, (h16)b.w};
    *(h16x8*)&W16s[(size_t)g * 8] = h;
}

// ---------------------------------------------------------------------------
// Conv-as-GEMM: per (b, nt, mat): D[128 o x 128 n], K = 1024 in chunks of 32.
// W staged by async global_load_lds (pre-swizzled), x by register prefetch.
// One barrier per K-chunk. qt/kt out as [b][n][o], vt as [b][o][n], fp16.
// ---------------------------------------------------------------------------
__global__ __launch_bounds__(256, 2) void conv_qkv(
    const float* __restrict__ x, const h16* __restrict__ W16s,
    const float* __restrict__ bq, const float* __restrict__ bk,
    const float* __restrict__ bv,
    h16* __restrict__ qt, h16* __restrict__ kt, h16* __restrict__ vt)
{
    const int nt  = blockIdx.x;          // 32 tiles of 128 n
    const int mat = blockIdx.y;
    const int b   = blockIdx.z;
    const float* bm = (mat == 0) ? bq : (mat == 1) ? bk : bv;
    const int tid = threadIdx.x, lane = tid & 63, wv = tid >> 6;
    const int lr = lane & 15, qd = lane >> 4;
    const int o_w = 64 * (wv >> 1), n_w = 64 * (wv & 1);

    __shared__ __align__(16) char smem[38400];
    // [0,16384): Wl[2] 8192 each; [16384,37888): Pl[2] 10752 each; [37888,38400): bias
    float* biasl = (float*)(smem + 37888);
    if (tid < 128) biasl[tid] = bm[tid];

    const h16* Wbase = W16s + (size_t)mat * 32 * 512 * 8;

    auto dmaW = [&](int kc, int bufsel) {
        const h16* g = Wbase + ((size_t)kc * 512 + wv * 128) * 8;
        char* l = smem + bufsel * 8192 + wv * 2048;
#pragma unroll
        for (int j = 0; j < 2; ++j)
            async16(g + (size_t)(j * 64 + lane) * 8, l + j * 1024);
    };

    f32x4 xr[4];
    auto xload = [&](int kc) {
#pragma unroll
        for (int j = 0; j < 4; ++j) {
            int s = tid + 256 * j;
            int n_l = s & 127, kh = (s >> 7) & 3, cc = s >> 9;
            xr[j] = *(const f32x4*)&x[(((size_t)(b * 64 + kc * 2 + cc) * 256)
                     + 8 * nt + 4 * (n_l >> 6) + kh) * 256 + 4 * (n_l & 63)];
        }
    };
    auto xwrite = [&](int bufsel) {
        h16* P = (h16*)(smem + 16384 + bufsel * 10752);
#pragma unroll
        for (int j = 0; j < 4; ++j) {
            int s = tid + 256 * j;
            int n_l = s & 127, kh = (s >> 7) & 3, cc = s >> 9;
            h16x4 h = {(h16)xr[j].x, (h16)xr[j].y, (h16)xr[j].z, (h16)xr[j].w};
            *(h16x4*)&P[n_l * 42 + cc * 16 + kh * 4] = h;
        }
    };

    f32x4 acc[4][4];
#pragma unroll
    for (int a = 0; a < 4; ++a)
#pragma unroll
        for (int c = 0; c < 4; ++c) acc[a][c] = (f32x4){0.f, 0.f, 0.f, 0.f};

    xload(0);
    dmaW(0, 0);
    xwrite(0);
    __syncthreads();

#pragma unroll 2
    for (int kc = 0; kc < 32; ++kc) {
        int c = kc & 1;
        if (kc + 1 < 32) { dmaW(kc + 1, 1 - c); xload(kc + 1); }

        h16* Wl = (h16*)(smem + c * 8192);
        h16* Pl = (h16*)(smem + 16384 + c * 10752);
        h16x8 af[4], bf[4];
#pragma unroll
        for (int to = 0; to < 4; ++to) {
            int o = o_w + 16 * to + lr;
            af[to] = *(const h16x8*)&Wl[(size_t)(o * 4 + (qd ^ ((o >> 1) & 3))) * 8];
        }
#pragma unroll
        for (int tn = 0; tn < 4; ++tn)
            bf[tn] = *(const h16x8*)&Pl[(n_w + 16 * tn + lr) * 42 + 8 * qd];
#pragma unroll
        for (int to = 0; to < 4; ++to)
#pragma unroll
            for (int tn = 0; tn < 4; ++tn)
                acc[to][tn] = __builtin_amdgcn_mfma_f32_16x16x32_f16(af[to], bf[tn], acc[to][tn], 0, 0, 0);

        if (kc + 1 < 32) xwrite(1 - c);
        __syncthreads();
    }

    const int n0 = nt * 128;
    if (mat < 2) {
        h16* bnc = (h16*)smem;   // [128 n][130 o]
#pragma unroll
        for (int to = 0; to < 4; ++to)
#pragma unroll
            for (int tn = 0; tn < 4; ++tn)
#pragma unroll
                for (int r = 0; r < 4; ++r) {
                    int o_l = o_w + 16 * to + 4 * qd + r;
                    int n_l = n_w + 16 * tn + lr;
                    bnc[n_l * 130 + o_l] = (h16)(acc[to][tn][r] + biasl[o_l]);
                }
        __syncthreads();
        h16* dst = (mat == 0) ? qt : kt;
#pragma unroll
        for (int j = 0; j < 16; ++j) {
            int s = tid + 256 * j;
            int n = s >> 5, o4 = s & 31;
            h16x4 h = *(h16x4*)&bnc[n * 130 + 4 * o4];
            *(h16x4*)(dst + ((size_t)(b * NP + n0 + n)) * OD + 4 * o4) = h;
        }
    } else {
        h16* bnc = (h16*)smem;   // [128 o][136 n]
#pragma unroll
        for (int to = 0; to < 4; ++to)
#pragma unroll
            for (int tn = 0; tn < 4; ++tn)
#pragma unroll
                for (int r = 0; r < 4; ++r) {
                    int o_l = o_w + 16 * to + 4 * qd + r;
                    int n_l = n_w + 16 * tn + lr;
                    bnc[o_l * 136 + n_l] = (h16)(acc[to][tn][r] + biasl[o_l]);
                }
        __syncthreads();
#pragma unroll
        for (int j = 0; j < 8; ++j) {
            int s = tid + 256 * j;
            int o = s >> 4, n8 = s & 15;
            h16x8 h = *(h16x8*)&bnc[o * 136 + 8 * n8];
            *(h16x8*)(vt + ((size_t)(b * OD + o)) * NP + n0 + 8 * n8) = h;
        }
    }
}

// ---------------------------------------------------------------------------
// Flash attention, split-K over 4 m-ranges. Block = 4 waves, 128 Q rows
// (32/wave). K/V double-buffered via global_load_lds (swizzled, 64 KB LDS
// total); P reuses the spent K buffer. DPP softmax reductions.
// Writes normalized fp16 partials + (m,l) stats.
// ---------------------------------------------------------------------------
__global__ __launch_bounds__(256, 2) void flash_attn(
    const h16* __restrict__ qt, const h16* __restrict__ kt,
    const h16* __restrict__ vt, h16* __restrict__ po, float* __restrict__ ml)
{
    const int nt = blockIdx.x;   // 32 tiles of 128 rows
    const int sp = blockIdx.y;   // 4 splits of 1024 m
    const int b  = blockIdx.z;
    const int tid = threadIdx.x, lane = tid & 63, wv = tid >> 6;
    const int lr = lane & 15, qd = lane >> 4;

    __shared__ __align__(16) char smem[65536];
    // K[2]: 0,16384 ; V[2]: 32768,49152

    // Q fragments: A[row n = lr][k o = 32kc+8qd+j], register-resident
    h16x8 qf[2][4];
#pragma unroll
    for (int rt = 0; rt < 2; ++rt)
#pragma unroll
        for (int kc = 0; kc < 4; ++kc)
            qf[rt][kc] = *(const h16x8*)&qt[((size_t)(b * NP + nt * 128 + 32 * wv + 16 * rt + lr)) * OD
                                            + 32 * kc + 8 * qd];

    float m_run[2][4], l_run[2][4];
#pragma unroll
    for (int rt = 0; rt < 2; ++rt)
#pragma unroll
        for (int r = 0; r < 4; ++r) { m_run[rt][r] = -1e30f; l_run[rt][r] = 0.f; }
    f32x4 oacc[2][8];
#pragma unroll
    for (int rt = 0; rt < 2; ++rt)
#pragma unroll
        for (int t = 0; t < 8; ++t) oacc[rt][t] = (f32x4){0.f, 0.f, 0.f, 0.f};

    auto dma = [&](int it, int bufsel) {
        int m0 = sp * 1024 + it * 64;
        char* Kb = smem + bufsel * 16384;
        char* Vb = smem + 32768 + bufsel * 16384;
#pragma unroll
        for (int j = 0; j < 4; ++j) {
            int s = wv * 256 + j * 64 + lane;
            int m_l = s >> 4, cst = s & 15, csrc = cst ^ (m_l & 15);
            async16(&kt[((size_t)(b * NP + m0 + m_l)) * OD + 8 * csrc],
                    Kb + (size_t)(wv * 256 + j * 64) * 16);
        }
#pragma unroll
        for (int j = 0; j < 4; ++j) {
            int s = wv * 256 + j * 64 + lane;
            int o = s >> 3, cst = s & 7, csrc = cst ^ (o & 7);
            async16(&vt[((size_t)(b * OD + o)) * NP + m0 + 8 * csrc],
                    Vb + (size_t)(wv * 256 + j * 64) * 16);
        }
    };

    dma(0, 0);
    __syncthreads();

#pragma unroll 2
    for (int it = 0; it < 16; ++it) {
        int c = it & 1;
        h16* Kb = (h16*)(smem + c * 16384);
        h16* Vb = (h16*)(smem + 32768 + c * 16384);

        // S = Q K^T : rows n = 4qd+r (per rt tile), cols m = 16t+lr
        f32x4 sc[2][4];
#pragma unroll
        for (int rt = 0; rt < 2; ++rt)
#pragma unroll
            for (int t = 0; t < 4; ++t) sc[rt][t] = (f32x4){0.f, 0.f, 0.f, 0.f};
#pragma unroll
        for (int t = 0; t < 4; ++t)
#pragma unroll
            for (int kc = 0; kc < 4; ++kc) {
                int mrow = 16 * t + lr;
                h16x8 bf = *(const h16x8*)&Kb[(size_t)(mrow * 16 + ((4 * kc + qd) ^ lr)) * 8];
                sc[0][t] = __builtin_amdgcn_mfma_f32_16x16x32_f16(qf[0][kc], bf, sc[0][t], 0, 0, 0);
                sc[1][t] = __builtin_amdgcn_mfma_f32_16x16x32_f16(qf[1][kc], bf, sc[1][t], 0, 0, 0);
            }

        // online softmax, DPP row reductions across the 16 lanes of each quad
        float al[2][4];
#pragma unroll
        for (int rt = 0; rt < 2; ++rt)
#pragma unroll
            for (int r = 0; r < 4; ++r) {
                float m1 = fmaxf(fmaxf(sc[rt][0][r], sc[rt][1][r]),
                                 fmaxf(sc[rt][2][r], sc[rt][3][r]));
                m1 = rmax16(m1);
                float mn = fmaxf(m_run[rt][r], m1);
                al[rt][r] = __expf(m_run[rt][r] - mn);
                m_run[rt][r] = mn;
                float rs = 0.f;
#pragma unroll
                for (int t = 0; t < 4; ++t) {
                    float e = __expf(sc[rt][t][r] - mn);
                    sc[rt][t][r] = e;
                    rs += e;
                }
                rs = rsum16(rs);
                l_run[rt][r] = l_run[rt][r] * al[rt][r] + rs;
            }
#pragma unroll
        for (int rt = 0; rt < 2; ++rt)
#pragma unroll
            for (int to = 0; to < 8; ++to)
#pragma unroll
                for (int r = 0; r < 4; ++r) oacc[rt][to][r] *= al[rt][r];

        __syncthreads();                 // all waves done reading K[c]
        if (it + 1 < 16) dma(it + 1, 1 - c);

        // P: D-layout -> swizzled wave region inside spent K buffer
        h16* Pw = (h16*)(smem + c * 16384 + wv * 4096);
#pragma unroll
        for (int rt = 0; rt < 2; ++rt)
#pragma unroll
            for (int t = 0; t < 4; ++t)
#pragma unroll
                for (int r = 0; r < 4; ++r) {
                    int n2 = 16 * rt + 4 * qd + r;
                    int m = 16 * t + lr;
                    Pw[n2 * 64 + (((m >> 3) ^ (n2 & 7)) * 8) + (m & 7)] = (h16)sc[rt][t][r];
                }
        h16x8 pf[2][2];
#pragma unroll
        for (int rt = 0; rt < 2; ++rt)
#pragma unroll
            for (int kc2 = 0; kc2 < 2; ++kc2) {
                int n3 = 16 * rt + lr;
                pf[rt][kc2] = *(const h16x8*)&Pw[n3 * 64 + (((4 * kc2 + qd) ^ (n3 & 7)) * 8)];
            }
#pragma unroll
        for (int to = 0; to < 8; ++to)
#pragma unroll
            for (int kc2 = 0; kc2 < 2; ++kc2) {
                int orow = 16 * to + lr;
                h16x8 bvf = *(const h16x8*)&Vb[(size_t)(orow * 8 + ((4 * kc2 + qd) ^ (orow & 7))) * 8];
                oacc[0][to] = __builtin_amdgcn_mfma_f32_16x16x32_f16(pf[0][kc2], bvf, oacc[0][to], 0, 0, 0);
                oacc[1][to] = __builtin_amdgcn_mfma_f32_16x16x32_f16(pf[1][kc2], bvf, oacc[1][to], 0, 0, 0);
            }
        __syncthreads();                 // V[c]/P done; DMA drained
    }

    // stats + normalized fp16 partials
    if (lr == 0) {
#pragma unroll
        for (int rt = 0; rt < 2; ++rt)
#pragma unroll
            for (int r = 0; r < 4; ++r) {
                int n = nt * 128 + 32 * wv + 16 * rt + 4 * qd + r;
                size_t idx = ((size_t)(sp * 4 + b) * NP + n) * 2;
                ml[idx] = m_run[rt][r];
                ml[idx + 1] = l_run[rt][r];
            }
    }
    float inv[2][4];
#pragma unroll
    for (int rt = 0; rt < 2; ++rt)
#pragma unroll
        for (int r = 0; r < 4; ++r) inv[rt][r] = 1.f / l_run[rt][r];
#pragma unroll
    for (int rt = 0; rt < 2; ++rt)
#pragma unroll
        for (int to = 0; to < 8; ++to)
#pragma unroll
            for (int r = 0; r < 4; ++r) {
                int n = nt * 128 + 32 * wv + 16 * rt + 4 * qd + r;
                po[((size_t)(sp * 4 + b) * NP + n) * OD + 16 * to + lr] =
                    (h16)(oacc[rt][to][r] * inv[rt][r]);
            }
}

// ---------------------------------------------------------------------------
// Combine 4 split partials -> out[b][o][n] fp32.
// ---------------------------------------------------------------------------
__global__ __launch_bounds__(256) void combine(
    const h16* __restrict__ po, const float* __restrict__ ml,
    float* __restrict__ out)
{
    const int nt = blockIdx.x;   // 64 tiles of 64 n
    const int b  = blockIdx.y;
    const int n0 = nt * 64, tid = threadIdx.x;
    __shared__ float w[4][64];
    __shared__ float bn[64 * 130];

    if (tid < 64) {
        int n = n0 + tid;
        float m[4], l[4], M = -1e30f;
#pragma unroll
        for (int s = 0; s < 4; ++s) {
            size_t idx = ((size_t)(s * 4 + b) * NP + n) * 2;
            m[s] = ml[idx]; l[s] = ml[idx + 1];
            M = fmaxf(M, m[s]);
        }
        float e[4], d = 0.f;
#pragma unroll
        for (int s = 0; s < 4; ++s) { e[s] = l[s] * __expf(m[s] - M); d += e[s]; }
        float id = 1.f / d;
#pragma unroll
        for (int s = 0; s < 4; ++s) w[s][tid] = e[s] * id;
    }
    __syncthreads();

#pragma unroll
    for (int j = 0; j < 4; ++j) {
        int s = tid + 256 * j;
        int n = s >> 4, oc = s & 15;
        float acc[8];
#pragma unroll
        for (int k = 0; k < 8; ++k) acc[k] = 0.f;
#pragma unroll
        for (int sp = 0; sp < 4; ++sp) {
            h16x8 v = *(const h16x8*)&po[((size_t)(sp * 4 + b) * NP + n0 + n) * OD + 8 * oc];
            float ww = w[sp][n];
#pragma unroll
            for (int k = 0; k < 8; ++k) acc[k] += ww * (float)v[k];
        }
#pragma unroll
        for (int k = 0; k < 8; ++k) bn[n * 130 + 8 * oc + k] = acc[k];
    }
    __syncthreads();

#pragma unroll
    for (int j = 0; j < 8; ++j) {
        int s = tid + 256 * j;
        int o = s >> 4, n4 = s & 15;
        f32x4 r = {bn[(4 * n4 + 0) * 130 + o], bn[(4 * n4 + 1) * 130 + o],
                   bn[(4 * n4 + 2) * 130 + o], bn[(4 * n4 + 3) * 130 + o]};
        *(f32x4*)&out[((size_t)(b * OD + o)) * NP + n0 + 4 * n4] = r;
    }
}

extern "C" void kernel_launch(void* const* d_in, const int* in_sizes, int n_in,
                              void* d_out, int out_size, void* d_ws, size_t ws_size,
                              hipStream_t stream) {
    const float* x  = (const float*)d_in[0];
    const float* Wq = (const float*)d_in[1];
    const float* bq = (const float*)d_in[2];
    const float* Wk = (const float*)d_in[3];
    const float* bk = (const float*)d_in[4];
    const float* Wv = (const float*)d_in[5];
    const float* bv = (const float*)d_in[6];

    h16* qtp  = (h16*)d_ws;                                  // 4 MB
    h16* ktp  = qtp + (size_t)NB * NP * OD;                  // 4 MB
    h16* vtp  = ktp + (size_t)NB * NP * OD;                  // 4 MB
    h16* W16s = vtp + (size_t)NB * NP * OD;                  // 768 KB
    h16* po   = W16s + (size_t)3 * 32 * 512 * 8;             // 16 MB
    float* ml = (float*)(po + (size_t)4 * NB * NP * OD);     // 512 KB
    float* out = (float*)d_out;

    wcvt<<<dim3(192), 256, 0, stream>>>(Wq, Wk, Wv, W16s);
    conv_qkv<<<dim3(32, 3, NB), 256, 0, stream>>>(x, W16s, bq, bk, bv, qtp, ktp, vtp);
    flash_attn<<<dim3(32, 4, NB), 256, 0, stream>>>(qtp, ktp, vtp, po, ml);
    combine<<<dim3(64, NB), 256, 0, stream>>>(po, ml, out);
}

// Round 3
// 205.025 us; speedup vs baseline: 1.4997x; 1.4997x over previous
//
#include <hip/hip_runtime.h>
#include <cstdint>
#include <cstddef>

#define NB 4
#define NP 4096
#define OD 128

typedef _Float16 h16;
typedef _Float16 h16x8 __attribute__((ext_vector_type(8)));
typedef _Float16 h16x4 __attribute__((ext_vector_type(4)));
typedef float    f32x4 __attribute__((ext_vector_type(4)));

__device__ __forceinline__ void async16(const void* g, void* l) {
    __builtin_amdgcn_global_load_lds(
        (const __attribute__((address_space(1))) void*)g,
        (__attribute__((address_space(3))) void*)l, 16, 0, 0);
}

// ---------------------------------------------------------------------------
// W fp32 -> fp16, pre-swizzled LDS image: per (mat,kc): 512 slots of 16B,
// slot = o*4 + csw, content = k-chunk (csw ^ ((o>>1)&3)) of 8 halfs.
// ---------------------------------------------------------------------------
__global__ __launch_bounds__(256) void wcvt(
    const float* __restrict__ Wq, const float* __restrict__ Wk,
    const float* __restrict__ Wv, h16* __restrict__ W16s)
{
    int g = blockIdx.x * 256 + threadIdx.x;        // 49152 slots
    int mat = g >> 14, r = g & 16383;
    int kc = r >> 9, q = r & 511, o = q >> 2, csw = q & 3;
    int c = csw ^ ((o >> 1) & 3);
    const float* W = (mat == 0) ? Wq : (mat == 1) ? Wk : Wv;
    const float* src = W + (size_t)o * 1024 + kc * 32 + 8 * c;
    f32x4 a = *(const f32x4*)src;
    f32x4 b = *(const f32x4*)(src + 4);
    h16x8 h = {(h16)a.x, (h16)a.y, (h16)a.z, (h16)a.w,
               (h16)b.x, (h16)b.y, (h16)b.z, (h16)b.w};
    *(h16x8*)&W16s[(size_t)g * 8] = h;
}

// ---------------------------------------------------------------------------
// Fused conv for Q,K,V in one block: tile 128o x 64n, x staged once per
// K-chunk and reused by all 3 mats. W via triple-buffered global_load_lds,
// x via 2-deep register prefetch. One barrier per K-chunk.
// qt/kt out [b][n][o]; vt out [b][o][n'] with n' permuted within 32-groups
// (pn = ((n>>2)&3)*8 + ((n>>4)&1)*4 + (n&3)) to make flash V-fragments b128.
// ---------------------------------------------------------------------------
__global__ __launch_bounds__(256, 2) void conv_qkv(
    const float* __restrict__ x, const h16* __restrict__ W16s,
    const float* __restrict__ bq, const float* __restrict__ bk,
    const float* __restrict__ bv,
    h16* __restrict__ qt, h16* __restrict__ kt, h16* __restrict__ vt)
{
    const int nt = blockIdx.x;            // 64 tiles of 64 n (one patch row)
    const int b  = blockIdx.y;
    const int tid = threadIdx.x, lane = tid & 63, wv = tid >> 6;
    const int lr = lane & 15, qd = lane >> 4;
    const int o_w = 32 * wv;              // wave: 32 o x 64 n

    __shared__ __align__(16) char smem[85504];
    // Wbuf[3] @ 0/24576/49152 (each: 3 mats * 8192); xb[2] @ 73728/78848
    // (each 64*40*2=5120); bias @ 83968 (3*128*4)
    float* biasl = (float*)(smem + 83968);
    if (tid < 128) {
        biasl[tid] = bq[tid]; biasl[128 + tid] = bk[tid]; biasl[256 + tid] = bv[tid];
    }

    auto dmaW = [&](int kc, int bs) {
#pragma unroll
        for (int t = 0; t < 6; ++t) {
            int grp = wv * 6 + t;               // 24 groups of 64 slots
            int mat = grp >> 3, sg = grp & 7;
            async16(W16s + ((size_t)(mat * 32 + kc) * 512 + sg * 64 + lane) * 8,
                    smem + bs * 24576 + mat * 8192 + sg * 1024);
        }
    };

    f32x4 xr[2][2];
    auto xload = [&](int kc, int sl) {
        int n = tid >> 2, kg = tid & 3;
        int c = kg >> 1, kh2 = (kg & 1) * 2;
        const float* p = &x[(((size_t)(b * 64 + 2 * kc + c) * 256) + 4 * nt + kh2) * 256 + 4 * n];
        xr[sl][0] = *(const f32x4*)p;
        xr[sl][1] = *(const f32x4*)(p + 256);
    };
    auto xwrite = [&](int sl, int xbs) {
        int n = tid >> 2, kg = tid & 3;
        int c = kg >> 1, kh2 = (kg & 1) * 2;
        h16x8 h = {(h16)xr[sl][0].x, (h16)xr[sl][0].y, (h16)xr[sl][0].z, (h16)xr[sl][0].w,
                   (h16)xr[sl][1].x, (h16)xr[sl][1].y, (h16)xr[sl][1].z, (h16)xr[sl][1].w};
        *(h16x8*)(smem + 73728 + xbs * 5120 + n * 80 + c * 32 + kh2 * 8) = h;
    };

    f32x4 acc[3][2][4];
#pragma unroll
    for (int m = 0; m < 3; ++m)
#pragma unroll
        for (int a = 0; a < 2; ++a)
#pragma unroll
            for (int c = 0; c < 4; ++c) acc[m][a][c] = (f32x4){0.f, 0.f, 0.f, 0.f};

    xload(0, 0); dmaW(0, 0);
    xload(1, 1); dmaW(1, 1);
    xwrite(0, 0);
    __syncthreads();

    int wb = 0;
#pragma unroll 2
    for (int kc = 0; kc < 32; ++kc) {
        int xbs = kc & 1;
        if (kc + 2 < 32) {
            dmaW(kc + 2, (wb == 0) ? 2 : wb - 1);   // (kc+2)%3
            xload(kc + 2, xbs);
        }
        const h16* Xl = (const h16*)(smem + 73728 + xbs * 5120);
        const char* Wl = smem + wb * 24576;

        h16x8 bf[4];
#pragma unroll
        for (int tn = 0; tn < 4; ++tn)
            bf[tn] = *(const h16x8*)&Xl[(16 * tn + lr) * 40 + 8 * qd];
#pragma unroll
        for (int mat = 0; mat < 3; ++mat) {
            h16x8 af[2];
#pragma unroll
            for (int to = 0; to < 2; ++to) {
                int o = o_w + 16 * to + lr;
                af[to] = *(const h16x8*)(Wl + mat * 8192 + (size_t)(o * 4 + (qd ^ ((o >> 1) & 3))) * 16);
            }
#pragma unroll
            for (int to = 0; to < 2; ++to)
#pragma unroll
                for (int tn = 0; tn < 4; ++tn)
                    acc[mat][to][tn] = __builtin_amdgcn_mfma_f32_16x16x32_f16(af[to], bf[tn], acc[mat][to][tn], 0, 0, 0);
        }
        if (kc + 1 < 32) xwrite((kc + 1) & 1, 1 - xbs);
        wb = (wb == 2) ? 0 : wb + 1;
        __syncthreads();
    }

    const int n0 = nt * 64;
    // Q, K: [b][n][o] via bounce [64 n][136 o]
#pragma unroll
    for (int mat = 0; mat < 2; ++mat) {
        h16* bnc = (h16*)smem;
#pragma unroll
        for (int to = 0; to < 2; ++to)
#pragma unroll
            for (int tn = 0; tn < 4; ++tn) {
                int ob = o_w + 16 * to + 4 * qd;
                int n  = 16 * tn + lr;
                h16x4 hv = {(h16)(acc[mat][to][tn][0] + biasl[mat * 128 + ob]),
                            (h16)(acc[mat][to][tn][1] + biasl[mat * 128 + ob + 1]),
                            (h16)(acc[mat][to][tn][2] + biasl[mat * 128 + ob + 2]),
                            (h16)(acc[mat][to][tn][3] + biasl[mat * 128 + ob + 3])};
                *(h16x4*)&bnc[n * 136 + ob] = hv;
            }
        __syncthreads();
        h16* dst = mat ? kt : qt;
#pragma unroll
        for (int j = 0; j < 4; ++j) {
            int s = tid + 256 * j;
            int n = s >> 4, oc = s & 15;
            *(h16x8*)(dst + ((size_t)(b * NP + n0 + n)) * OD + 8 * oc) = *(h16x8*)&bnc[n * 136 + 8 * oc];
        }
        __syncthreads();
    }
    // V: [b][o][n'] permuted, via bounce [128 o][72 n]
    {
        h16* bnc = (h16*)smem;
#pragma unroll
        for (int to = 0; to < 2; ++to)
#pragma unroll
            for (int tn = 0; tn < 4; ++tn)
#pragma unroll
                for (int r = 0; r < 4; ++r) {
                    int o = o_w + 16 * to + 4 * qd + r;
                    int n = 16 * tn + lr;
                    bnc[o * 72 + n] = (h16)(acc[2][to][tn][r] + biasl[256 + o]);
                }
        __syncthreads();
#pragma unroll
        for (int j = 0; j < 4; ++j) {
            int s = tid + 256 * j;
            int o = s >> 3, ch = s & 7;
            int g = ch >> 2, q2 = ch & 3;
            h16x8 hv;
#pragma unroll
            for (int r2 = 0; r2 < 8; ++r2) {
                int mt = r2 >> 2, r = r2 & 3;
                hv[r2] = bnc[o * 72 + 32 * g + 16 * mt + 4 * q2 + r];
            }
            *(h16x8*)(vt + ((size_t)(b * OD + o)) * NP + n0 + 32 * g + 8 * q2) = hv;
        }
    }
}

// ---------------------------------------------------------------------------
// Flash attention, split-K (SP splits). Block: 4 waves x 32 Q-rows = 128 rows.
// S^T = mfma(K_frag, Q_frag) so P exits in exactly the B-operand layout of
// mfma_f32_16x16x16_f16 -> PV with NO LDS transpose. BM=32 K/V double-buffered
// via global_load_lds (swizzled); one barrier per iteration.
// ---------------------------------------------------------------------------
template <int SP>
__global__ __launch_bounds__(256, 3) void flash_attn(
    const h16* __restrict__ qt, const h16* __restrict__ kt,
    const h16* __restrict__ vt, h16* __restrict__ po, float2* __restrict__ ml)
{
    constexpr int MR  = NP / SP;
    constexpr int NIT = MR / 32;
    const int nt = blockIdx.x, sp = blockIdx.y, b = blockIdx.z;
    const int tid = threadIdx.x, lane = tid & 63, wv = tid >> 6;
    const int lr = lane & 15, qd = lane >> 4;

    __shared__ __align__(16) char smem[32768];   // K[2]@0/8192, V[2]@16384/24576

    // Q fragments (B-operand): B[col n = lr][k o = 32kc+8qd+j]
    h16x8 qf[2][4];
#pragma unroll
    for (int rt = 0; rt < 2; ++rt)
#pragma unroll
        for (int kc = 0; kc < 4; ++kc)
            qf[rt][kc] = *(const h16x8*)&qt[((size_t)(b * NP + nt * 128 + 32 * wv + 16 * rt + lr)) * OD
                                            + 32 * kc + 8 * qd];

    float m_run[2] = {-1e30f, -1e30f}, l_run[2] = {0.f, 0.f};
    f32x4 oacc[2][8];
#pragma unroll
    for (int rt = 0; rt < 2; ++rt)
#pragma unroll
        for (int t = 0; t < 8; ++t) oacc[rt][t] = (f32x4){0.f, 0.f, 0.f, 0.f};

    auto dma = [&](int it, int bs) {
        int m0 = sp * MR + it * 32;
#pragma unroll
        for (int t = 0; t < 2; ++t) {            // K: 32m x 16 chunks
            int s = wv * 128 + t * 64 + lane;
            int m = s >> 4, cst = s & 15, csrc = cst ^ (m & 15);
            async16(kt + ((size_t)(b * NP + m0 + m)) * OD + 8 * csrc,
                    smem + bs * 8192 + (wv * 128 + t * 64) * 16);
        }
#pragma unroll
        for (int t = 0; t < 2; ++t) {            // V: 128o x 4 chunks (permuted m)
            int s = wv * 128 + t * 64 + lane;
            int o = s >> 2, cst = s & 3, csrc = cst ^ ((o >> 1) & 3);
            async16(vt + ((size_t)(b * OD + o)) * NP + m0 + 8 * csrc,
                    smem + 16384 + bs * 8192 + (wv * 128 + t * 64) * 16);
        }
    };

    dma(0, 0);
    __syncthreads();

#pragma unroll 2
    for (int it = 0; it < NIT; ++it) {
        int c = it & 1;
        if (it + 1 < NIT) dma(it + 1, 1 - c);
        const h16* Kb = (const h16*)(smem + c * 8192);
        const h16* Vb = (const h16*)(smem + 16384 + c * 8192);

        // S^T: D[row m = 16mt+4qd+r][col n = lr]
        f32x4 sc[2][2];
#pragma unroll
        for (int rt = 0; rt < 2; ++rt)
#pragma unroll
            for (int mt = 0; mt < 2; ++mt) sc[rt][mt] = (f32x4){0.f, 0.f, 0.f, 0.f};
#pragma unroll
        for (int mt = 0; mt < 2; ++mt)
#pragma unroll
            for (int kc = 0; kc < 4; ++kc) {
                h16x8 kf = *(const h16x8*)&Kb[(size_t)((16 * mt + lr) * 16 + ((4 * kc + qd) ^ lr)) * 8];
                sc[0][mt] = __builtin_amdgcn_mfma_f32_16x16x32_f16(kf, qf[0][kc], sc[0][mt], 0, 0, 0);
                sc[1][mt] = __builtin_amdgcn_mfma_f32_16x16x32_f16(kf, qf[1][kc], sc[1][mt], 0, 0, 0);
            }

        // online softmax: per lane 8 m-values for its n=lr; reduce qd via shfl
        h16x4 pf[2][2];
        float al[2];
#pragma unroll
        for (int rt = 0; rt < 2; ++rt) {
            float mx = fmaxf(fmaxf(fmaxf(sc[rt][0][0], sc[rt][0][1]), fmaxf(sc[rt][0][2], sc[rt][0][3])),
                             fmaxf(fmaxf(sc[rt][1][0], sc[rt][1][1]), fmaxf(sc[rt][1][2], sc[rt][1][3])));
            mx = fmaxf(mx, __shfl_xor(mx, 16));
            mx = fmaxf(mx, __shfl_xor(mx, 32));
            float mn = fmaxf(m_run[rt], mx);
            al[rt] = __expf(m_run[rt] - mn);
            m_run[rt] = mn;
            float rs = 0.f;
#pragma unroll
            for (int mt = 0; mt < 2; ++mt)
#pragma unroll
                for (int r = 0; r < 4; ++r) {
                    float e = __expf(sc[rt][mt][r] - mn);
                    sc[rt][mt][r] = e;
                    rs += e;
                }
            rs += __shfl_xor(rs, 16);
            rs += __shfl_xor(rs, 32);
            l_run[rt] = l_run[rt] * al[rt] + rs;
            pf[rt][0] = (h16x4){(h16)sc[rt][0][0], (h16)sc[rt][0][1], (h16)sc[rt][0][2], (h16)sc[rt][0][3]};
            pf[rt][1] = (h16x4){(h16)sc[rt][1][0], (h16)sc[rt][1][1], (h16)sc[rt][1][2], (h16)sc[rt][1][3]};
        }
#pragma unroll
        for (int rt = 0; rt < 2; ++rt)
#pragma unroll
            for (int to = 0; to < 8; ++to)
#pragma unroll
                for (int r = 0; r < 4; ++r) oacc[rt][to][r] *= al[rt];

        // PV: out^T[o][n] += V[o][m] * P^T[m][n]  (16x16x16, P from registers)
#pragma unroll
        for (int to = 0; to < 8; ++to) {
            int o = 16 * to + lr;
            h16x8 vv = *(const h16x8*)&Vb[(size_t)(o * 4 + (qd ^ ((o >> 1) & 3))) * 8];
            h16x4 va = __builtin_shufflevector(vv, vv, 0, 1, 2, 3);   // m = 4qd+j (mt 0)
            h16x4 vb2 = __builtin_shufflevector(vv, vv, 4, 5, 6, 7);  // mt 1
#pragma unroll
            for (int rt = 0; rt < 2; ++rt) {
                oacc[rt][to] = __builtin_amdgcn_mfma_f32_16x16x16f16(va,  pf[rt][0], oacc[rt][to], 0, 0, 0);
                oacc[rt][to] = __builtin_amdgcn_mfma_f32_16x16x16f16(vb2, pf[rt][1], oacc[rt][to], 0, 0, 0);
            }
        }
        __syncthreads();   // retire K/V[c] reads; drain DMA for next iter
    }

    // epilogue: normalized fp16 partials + (m,l)
    const size_t nbase = (size_t)(sp * NB + b) * NP + nt * 128 + 32 * wv;
    if (qd == 0) {
#pragma unroll
        for (int rt = 0; rt < 2; ++rt)
            ml[nbase + 16 * rt + lr] = make_float2(m_run[rt], l_run[rt]);
    }
    float inv[2] = {1.f / l_run[0], 1.f / l_run[1]};
#pragma unroll
    for (int rt = 0; rt < 2; ++rt)
#pragma unroll
        for (int to = 0; to < 8; ++to) {
            h16x4 hv = {(h16)(oacc[rt][to][0] * inv[rt]), (h16)(oacc[rt][to][1] * inv[rt]),
                        (h16)(oacc[rt][to][2] * inv[rt]), (h16)(oacc[rt][to][3] * inv[rt])};
            *(h16x4*)&po[(nbase + 16 * rt + lr) * OD + 16 * to + 4 * qd] = hv;
        }
}

// ---------------------------------------------------------------------------
// Combine SP split partials -> out[b][o][n] fp32.
// ---------------------------------------------------------------------------
template <int SP>
__global__ __launch_bounds__(256) void combine(
    const h16* __restrict__ po, const float2* __restrict__ ml,
    float* __restrict__ out)
{
    const int nt = blockIdx.x, b = blockIdx.y;
    const int n0 = nt * 64, tid = threadIdx.x;
    __shared__ float w[SP][64];
    __shared__ float bn[64 * 130];

    if (tid < 64) {
        int n = n0 + tid;
        float m[SP], l[SP], M = -1e30f;
#pragma unroll
        for (int s = 0; s < SP; ++s) {
            float2 v = ml[(size_t)(s * NB + b) * NP + n];
            m[s] = v.x; l[s] = v.y;
            M = fmaxf(M, m[s]);
        }
        float d = 0.f, e[SP];
#pragma unroll
        for (int s = 0; s < SP; ++s) { e[s] = l[s] * __expf(m[s] - M); d += e[s]; }
        float id = 1.f / d;
#pragma unroll
        for (int s = 0; s < SP; ++s) w[s][tid] = e[s] * id;
    }
    __syncthreads();

#pragma unroll
    for (int j = 0; j < 4; ++j) {
        int s = tid + 256 * j;
        int n = s >> 4, oc = s & 15;
        float acc[8];
#pragma unroll
        for (int k = 0; k < 8; ++k) acc[k] = 0.f;
#pragma unroll
        for (int sp = 0; sp < SP; ++sp) {
            h16x8 v = *(const h16x8*)&po[((size_t)(sp * NB + b) * NP + n0 + n) * OD + 8 * oc];
            float ww = w[sp][n];
#pragma unroll
            for (int k = 0; k < 8; ++k) acc[k] += ww * (float)v[k];
        }
#pragma unroll
        for (int k = 0; k < 8; ++k) bn[n * 130 + 8 * oc + k] = acc[k];
    }
    __syncthreads();

#pragma unroll
    for (int j = 0; j < 8; ++j) {
        int s = tid + 256 * j;
        int o = s >> 4, n4 = s & 15;
        f32x4 r = {bn[(4 * n4 + 0) * 130 + o], bn[(4 * n4 + 1) * 130 + o],
                   bn[(4 * n4 + 2) * 130 + o], bn[(4 * n4 + 3) * 130 + o]};
        *(f32x4*)&out[((size_t)(b * OD + o)) * NP + n0 + 4 * n4] = r;
    }
}

extern "C" void kernel_launch(void* const* d_in, const int* in_sizes, int n_in,
                              void* d_out, int out_size, void* d_ws, size_t ws_size,
                              hipStream_t stream) {
    const float* x  = (const float*)d_in[0];
    const float* Wq = (const float*)d_in[1];
    const float* bq = (const float*)d_in[2];
    const float* Wk = (const float*)d_in[3];
    const float* bk = (const float*)d_in[4];
    const float* Wv = (const float*)d_in[5];
    const float* bv = (const float*)d_in[6];

    h16* qtp  = (h16*)d_ws;                                  // 4 MB
    h16* ktp  = qtp + (size_t)NB * NP * OD;                  // 4 MB
    h16* vtp  = ktp + (size_t)NB * NP * OD;                  // 4 MB (permuted)
    h16* W16s = vtp + (size_t)NB * NP * OD;                  // 768 KB
    h16* po   = W16s + (size_t)3 * 32 * 512 * 8;             // SP*4 MB
    float* out = (float*)d_out;

    wcvt<<<dim3(192), 256, 0, stream>>>(Wq, Wk, Wv, W16s);
    conv_qkv<<<dim3(64, NB), 256, 0, stream>>>(x, W16s, bq, bk, bv, qtp, ktp, vtp);

    const size_t base = 13369344;   // bytes up to po
    const size_t need8 = base + (size_t)8 * NB * NP * OD * 2 + (size_t)8 * NB * NP * 8;
    if (ws_size >= need8) {
        float2* ml = (float2*)(po + (size_t)8 * NB * NP * OD);
        flash_attn<8><<<dim3(32, 8, NB), 256, 0, stream>>>(qtp, ktp, vtp, po, ml);
        combine<8><<<dim3(64, NB), 256, 0, stream>>>(po, ml, out);
    } else {
        float2* ml = (float2*)(po + (size_t)4 * NB * NP * OD);
        flash_attn<4><<<dim3(32, 4, NB), 256, 0, stream>>>(qtp, ktp, vtp, po, ml);
        combine<4><<<dim3(64, NB), 256, 0, stream>>>(po, ml, out);
    }
}